// Round 10
// baseline (416.022 us; speedup 1.0000x reference)
//
#include <hip/hip_runtime.h>

// MHA: cvt fp32->bf16 -> QKV GEMM (128x256 pipelined, LDS-coalesced epilogue,
//      V stored transposed) -> MFMA flash attention (T14 reg-staged K/V,
//      single-buffered LDS, 3 blocks/CU)
// B=2 S=2048 E=2048 NH=16 HD=128 ROTARY=32 base=1e4 NEG_INF=-1e4
#define B_    2
#define S_    2048
#define E_    2048
#define NH_   16
#define HD_   128
#define NQKV_ 6144
#define M_    4096
#define XN_   (M_ * E_)          // 8388608 X elements
#define NPAN  (E_ / 32)          // 64 K-panels of 32

typedef short bf16x8 __attribute__((ext_vector_type(8)));   // 8 bf16 (4 VGPRs)
typedef float f32x4  __attribute__((ext_vector_type(4)));   // MFMA C/D

typedef const __attribute__((address_space(1))) void* gas_t; // global addrspace
typedef __attribute__((address_space(3))) void*       las_t; // LDS addrspace

__device__ inline float b2f(unsigned short u) {
    return __uint_as_float(((unsigned int)u) << 16);
}
__device__ inline unsigned short f2b(float f) {             // RNE f32->bf16
    unsigned int x = __float_as_uint(f);
    x = x + 0x7fffu + ((x >> 16) & 1u);
    return (unsigned short)(x >> 16);
}
__device__ inline unsigned int pk2(float lo, float hi) {
    return (unsigned int)f2b(lo) | ((unsigned int)f2b(hi) << 16);
}

// ---------------------------------------------------------------------------
// Kernel 0: one-shot fp32 -> bf16 of X (8.39M) and W (12.58M) into workspace.
// ---------------------------------------------------------------------------
__global__ __launch_bounds__(256) void cvt_bf16(
    const float* __restrict__ X,
    const float* __restrict__ W,
    unsigned short* __restrict__ O)      // [XN_ of X][W follows]
{
    const long i = (long)(blockIdx.x * 256 + threadIdx.x) * 8;
    const float* src = (i < XN_) ? (X + i) : (W + (i - XN_));
    const float4 a = *(const float4*)(src);
    const float4 b = *(const float4*)(src + 4);
    uint4 o = { pk2(a.x, a.y), pk2(a.z, a.w), pk2(b.x, b.y), pk2(b.z, b.w) };
    *(uint4*)(O + i) = o;
}

// ---------------------------------------------------------------------------
// Kernel 1: QKV = Xb * Wb^T + bias, RoPE fused. BYTE-IDENTICAL to round 8
// (measured 121 us, FETCH 100MB, MfmaUtil 36% = 2-barrier structure ceiling).
// ---------------------------------------------------------------------------
__global__ __launch_bounds__(512, 4) void qkv_gemm(
    const unsigned short* __restrict__ Xb,   // bf16 [4096][2048]
    const unsigned short* __restrict__ Wb,   // bf16 [6144][2048]
    const float* __restrict__ bias,
    unsigned short* __restrict__ qb,
    unsigned short* __restrict__ kb,
    unsigned short* __restrict__ vt)         // bf16 [B][NH][HD][S]
{
    union GS {
        struct {
            unsigned short As[3][128 * 32];  // 24 KiB
            unsigned short Bs[3][256 * 32];  // 48 KiB
        } s;
        unsigned short Eqk[128 * 264];       // 67584 B (epilogue reuse)
        unsigned short Ev [256 * 136];       // 69632 B (epilogue reuse)
    };
    __shared__ __align__(16) GS gs;

    const int t    = threadIdx.x;            // 0..511
    const int lane = t & 63;
    const int w    = t >> 6;                 // 0..7
    const int wr   = w >> 2;                 // 0..1  (m half, 64 rows)
    const int wc   = w & 3;                  // 0..3  (n quarter, 64 cols)
    const int quad = (lane >> 4) & 3;
    const int l16  = lane & 15;

    // XCD-aware 2D-locality swizzle (bid&7 = XCD, 768 = 8 * 96):
    // XCD x -> n-slab {3x..3x+2} (W slab 3MB, L2-resident), m streamed.
    const int xcd = (int)blockIdx.x & 7;
    const int j   = (int)blockIdx.x >> 3;    // 0..95
    const int m0  = (j / 3) * 128;           // 0..31 -> 128-row tiles
    const int n0  = (xcd * 3 + (j % 3)) * 256; // 0..23 -> 256-col tiles

    auto stageA = [&](int p) {
        const int sl = p % 3;
        const int k0 = p * 32;
        const int ub  = w * 64;
        const int u   = ub + lane;
        const int row = u >> 2;
        const int ko  = (u & 3) ^ ((row >> 1) & 3);
        __builtin_amdgcn_global_load_lds(
            (gas_t)(Xb + (size_t)(m0 + row) * E_ + k0 + ko * 8),
            (las_t)&gs.s.As[sl][ub * 8], 16, 0, 0);
    };
    auto stageB = [&](int p) {
        const int sl = p % 3;
        const int k0 = p * 32;
        #pragma unroll
        for (int c = 0; c < 2; c++) {
            const int ub  = c * 512 + w * 64;
            const int u   = ub + lane;
            const int row = u >> 2;
            const int ko  = (u & 3) ^ ((row >> 1) & 3);
            __builtin_amdgcn_global_load_lds(
                (gas_t)(Wb + (size_t)(n0 + row) * E_ + k0 + ko * 8),
                (las_t)&gs.s.Bs[sl][ub * 8], 16, 0, 0);
        }
    };

    f32x4 acc[4][4];
    #pragma unroll
    for (int i = 0; i < 4; i++)
        #pragma unroll
        for (int j2 = 0; j2 < 4; j2++)
            #pragma unroll
            for (int r = 0; r < 4; r++) acc[i][j2][r] = 0.0f;

    stageA(0); stageB(0);
    stageA(1); stageB(1);
    asm volatile("s_waitcnt vmcnt(0)" ::: "memory");
    __builtin_amdgcn_s_barrier();

    for (int p = 0; p < NPAN; p++) {
        const int sl = p % 3;
        bf16x8 af[4], bfv[4];

        #pragma unroll
        for (int mf = 0; mf < 4; mf++) {
            const int row = wr * 64 + mf * 16 + l16;
            af[mf] = *(const bf16x8*)&gs.s.As[sl][row * 32 + (quad ^ ((row >> 1) & 3)) * 8];
        }
        #pragma unroll
        for (int nf = 0; nf < 4; nf++) {
            const int rb = wc * 64 + nf * 16 + l16;
            bfv[nf] = *(const bf16x8*)&gs.s.Bs[sl][rb * 32 + (quad ^ ((rb >> 1) & 3)) * 8];
        }

        if (p + 2 < NPAN) {
            stageA(p + 2); stageB(p + 2);
            asm volatile("s_waitcnt vmcnt(3)" ::: "memory");   // p+1 landed
        } else {
            asm volatile("s_waitcnt vmcnt(0)" ::: "memory");   // tail
        }
        __builtin_amdgcn_s_barrier();
        __builtin_amdgcn_s_setprio(1);
        #pragma unroll
        for (int mf = 0; mf < 4; mf++)
            #pragma unroll
            for (int nf = 0; nf < 4; nf++)
                acc[mf][nf] = __builtin_amdgcn_mfma_f32_16x16x32_bf16(
                    af[mf], bfv[nf], acc[mf][nf], 0, 0, 0);
        __builtin_amdgcn_s_setprio(0);
        __builtin_amdgcn_s_barrier();
    }

    // ---- bias + fused RoPE on registers
    const int which = n0 >> 11;                   // 0=q 1=k 2=v (const/block)

    float bv[4];
    #pragma unroll
    for (int nf = 0; nf < 4; nf++) bv[nf] = bias[n0 + wc * 64 + nf * 16 + l16];
    #pragma unroll
    for (int mi = 0; mi < 4; mi++)
        #pragma unroll
        for (int nf = 0; nf < 4; nf++)
            #pragma unroll
            for (int r = 0; r < 4; r++) acc[mi][nf][r] += bv[nf];

    // RoPE: tile spans 2 heads; head-local d<64 quarters are wc==0 / wc==2.
    if ((wc & 1) == 0 && which < 2) {
        const float inv = exp2f(-0.83048202372184059f * (float)l16); // 1e4^(-d/16)
        #pragma unroll
        for (int mi = 0; mi < 4; mi++) {
            #pragma unroll
            for (int r = 0; r < 4; r++) {
                const int m = m0 + wr * 64 + mi * 16 + quad * 4 + r;
                const int sdx = m & (S_ - 1);
                float c, sn;
                __sincosf((float)sdx * inv, &sn, &c);
                const float u1 = acc[mi][0][r], u2 = acc[mi][1][r];
                acc[mi][0][r] = u1 * c - u2 * sn;
                acc[mi][1][r] = u1 * sn + u2 * c;
            }
        }
    }

    // ---- LDS-staged coalesced stores (main loop's final barrier passed;
    // all As/Bs reads retired -> union reuse safe).
    const int hb = (n0 >> 7) & 15;                // head base of this tile
    const int bb = m0 >> 11;
    const int sb = m0 & (S_ - 1);
    if (which < 2) {
        unsigned short* dst = (which == 0) ? qb : kb;
        unsigned short* E = gs.Eqk;               // [128][264]
        #pragma unroll
        for (int mi = 0; mi < 4; mi++) {
            const int m = wr * 64 + mi * 16 + quad * 4;
            #pragma unroll
            for (int nf = 0; nf < 4; nf++) {
                const int col = wc * 64 + nf * 16 + l16;
                #pragma unroll
                for (int r = 0; r < 4; r++)
                    E[(m + r) * 264 + col] = f2b(acc[mi][nf][r]);
            }
        }
        __syncthreads();
        const int em  = t >> 2;                   // 0..127
        const int ecg = (t & 3) * 8;              // chunk base
        unsigned short* orow =
            dst + ((size_t)(bb * NH_ + hb) * S_ + sb + em) * HD_;
        #pragma unroll
        for (int i = 0; i < 8; i++) {
            const int chunk = ecg + i;            // 0..31
            const int hh = chunk >> 4;            // +0/1 within tile
            const int d  = (chunk & 15) * 8;
            uint4 vv = *(const uint4*)&E[em * 264 + chunk * 8];
            *(uint4*)&orow[(size_t)hh * (HD_ * S_) + d] = vv;
        }
    } else {
        unsigned short* E = gs.Ev;                // [256][136]
        #pragma unroll
        for (int mi = 0; mi < 4; mi++) {
            const int m = wr * 64 + mi * 16 + quad * 4;
            #pragma unroll
            for (int nf = 0; nf < 4; nf++) {
                const int col = wc * 64 + nf * 16 + l16;
                #pragma unroll
                for (int r = 0; r < 4; r++)
                    E[col * 136 + m + r] = f2b(acc[mi][nf][r]);
            }
        }
        __syncthreads();
        const int col = t >> 1;                   // 0..255
        const int cb  = (t & 1) * 8;              // chunk base 0/8
        const int hh  = hb + (col >> 7);
        const int d   = col & 127;
        unsigned short* vrow =
            vt + ((size_t)(bb * NH_ + hh) * HD_ + d) * S_ + sb;
        #pragma unroll
        for (int i = 0; i < 8; i++) {
            const int chunk = cb + i;             // 0..15
            uint4 vv = *(const uint4*)&E[col * 136 + chunk * 8];
            *(uint4*)&vrow[chunk * 8] = vv;
        }
    }
}

// ---------------------------------------------------------------------------
// Kernel 2: MFMA causal flash attention. ROUND-9: occupancy 2 -> 3 blocks/CU.
// Round-8 config (gload_lds dbuf) = 74.75 KB LDS = 2 blocks/CU = 2 waves/SIMD
// on a latency-bound kernel (~12% MfmaUtil, nothing saturated). Switch to
// T14 async-STAGE split: K/V SINGLE-buffered in LDS (41 KB -> 3 blocks/CU),
// tile t+1 global loads (8x uint4, V needs no pack: vt is d-major) issued at
// the TOP of iter t -> HBM/L2 latency hides under the whole QK/softmax/PV
// phase; ds_write after the reads-done barrier. 2 barriers/iter (was 1), but
// +50% waves/SIMD. Swizzle: ds_write unit' = unit ^ (row&7) (round-6
// verified K pattern + V analog); reads unchanged.
// Layouts (HW-verified 16x16x32_bf16): A[m=lane&15][k=quad*8+j];
// C/D row=quad*4+reg, col=lane&15.
// ---------------------------------------------------------------------------
#define PSTR 72
#define OSTR 132

__global__ __launch_bounds__(256, 3) void attn_mfma(
    const unsigned short* __restrict__ qb,
    const unsigned short* __restrict__ kb,
    const unsigned short* __restrict__ vt,
    float* __restrict__ out)
{
    union SM {
        struct {
            unsigned short Ks[64 * 128];       // 16384 B
            unsigned short Vs[128 * 64];       // 16384 B
            unsigned short Ps[4 * 16 * PSTR];  //  9216 B
        } a;                                   // 41984 B total -> 3 blocks/CU
        float Ow[4 * 16 * OSTR];               // 33792 B (epilogue reuse)
    };
    __shared__ __align__(16) SM sm;

    const int bid  = blockIdx.x;
    const int qt   = 31 - (bid >> 5);       // 64-row q-tile, heavy-first
    const int bh   = bid & 31;              // bid%8 spreads bh over XCDs;
    const int b    = bh >> 4;               // each XCD sees 4 bh -> 4MB K/V = L2
    const int h    = bh & 15;
    const int t    = threadIdx.x;
    const int lane = t & 63;
    const int w    = t >> 6;
    const int quad = lane >> 4;
    const int l16  = lane & 15;

    const int wrow0  = qt * 64 + w * 16;    // wave q-row base (16 rows)
    const int ntiles = qt + 1;              // K tiles of 64

    unsigned short* Pw = sm.a.Ps + w * 16 * PSTR;

    // staging maps: K row 0..63 (4 thr/row, 64B each); V d-row 0..127 (2/row)
    const int krow = t >> 2, kub = (t & 3) * 4;    // 16B-unit base 0..12
    const int vdrow = t >> 1, vub = (t & 1) * 4;   // 16B-unit base 0/4

    uint4 kr[4], vr[4];
    auto load_tile = [&](int kt2) {        // T14 issue-early: regs only
        const int s2 = kt2 * 64;
        const unsigned short* kg =
            kb + ((size_t)(bh * S_ + s2 + krow)) * HD_ + kub * 8;
        #pragma unroll
        for (int u = 0; u < 4; u++) kr[u] = *(const uint4*)(kg + u * 8);
        const unsigned short* vg =
            vt + ((size_t)(bh * HD_ + vdrow)) * S_ + s2 + vub * 8;
        #pragma unroll
        for (int u = 0; u < 4; u++) vr[u] = *(const uint4*)(vg + u * 8);
    };
    auto write_tile = [&]() {              // T14 write-late: swizzled b128
        #pragma unroll
        for (int u = 0; u < 4; u++)
            *(uint4*)&sm.a.Ks[krow * 128 + ((kub + u) ^ (krow & 7)) * 8] = kr[u];
        #pragma unroll
        for (int u = 0; u < 4; u++)
            *(uint4*)&sm.a.Vs[vdrow * 64 + ((vub + u) ^ (vdrow & 7)) * 8] = vr[u];
    };

    // Q A-fragments from global: k = c*32 + quad*8 + j
    bf16x8 qf[4];
    {
        const unsigned short* qp =
            qb + ((size_t)(bh * S_ + wrow0 + l16)) * HD_ + quad * 8;
        #pragma unroll
        for (int c = 0; c < 4; c++)
            qf[c] = *(const bf16x8*)(qp + c * 32);
    }

    f32x4 of[8];
    #pragma unroll
    for (int db = 0; db < 8; db++)
        #pragma unroll
        for (int r = 0; r < 4; r++) of[db][r] = 0.0f;
    float mr[4], lr[4];
    #pragma unroll
    for (int r = 0; r < 4; r++) { mr[r] = -1e30f; lr[r] = 0.0f; }

    // log2-domain softmax: scale' = (1/sqrt(128))*log2(e), mask' = -1e4*log2(e)
    const float scale2 = 0.12751744459892879f;
    const float mneg2  = -14426.950408889634f;

    load_tile(0);
    write_tile();
    __syncthreads();                 // tile 0 visible to all waves

    for (int kt = 0; kt < ntiles; kt++) {
        const int s0 = kt * 64;
        if (kt + 1 < ntiles) load_tile(kt + 1);   // latency under compute

        // ---- S = Q K^T (swizzled kf reads)
        f32x4 sf[4];
        #pragma unroll
        for (int nb = 0; nb < 4; nb++)
            #pragma unroll
            for (int r = 0; r < 4; r++) sf[nb][r] = 0.0f;
        #pragma unroll
        for (int c = 0; c < 4; c++) {
            #pragma unroll
            for (int nb = 0; nb < 4; nb++) {
                const int u = (c * 4 + quad) ^ (l16 & 7);
                bf16x8 kf = *(const bf16x8*)
                    &sm.a.Ks[(nb * 16 + l16) * 128 + u * 8];
                sf[nb] = __builtin_amdgcn_mfma_f32_16x16x32_bf16(
                    qf[c], kf, sf[nb], 0, 0, 0);
            }
        }

        // ---- scale + causal mask, log2 domain
        const bool need_mask = (s0 + 63 > wrow0);
        {
            const int qr0 = wrow0 + quad * 4;
            #pragma unroll
            for (int nb = 0; nb < 4; nb++) {
                const int kcol = s0 + nb * 16 + l16;
                #pragma unroll
                for (int r = 0; r < 4; r++) {
                    float s = sf[nb][r] * scale2;
                    if (need_mask && kcol > qr0 + r) s += mneg2;
                    sf[nb][r] = s;
                }
            }
        }

        // ---- online softmax (16-lane max reduce; lr partials; deferred
        //      rescale when no row max grew)
        {
            float mt4[4];
            #pragma unroll
            for (int r = 0; r < 4; r++) {
                float mt = fmaxf(fmaxf(sf[0][r], sf[1][r]),
                                 fmaxf(sf[2][r], sf[3][r]));
                mt = fmaxf(mt, __shfl_xor(mt, 1));
                mt = fmaxf(mt, __shfl_xor(mt, 2));
                mt = fmaxf(mt, __shfl_xor(mt, 4));
                mt = fmaxf(mt, __shfl_xor(mt, 8));
                mt4[r] = mt;
            }
            const bool grew = (mt4[0] > mr[0]) || (mt4[1] > mr[1]) ||
                              (mt4[2] > mr[2]) || (mt4[3] > mr[3]);
            if (__any(grew)) {
                float alpha[4];
                #pragma unroll
                for (int r = 0; r < 4; r++) {
                    const float mnew = fmaxf(mr[r], mt4[r]);
                    alpha[r] = __builtin_amdgcn_exp2f(mr[r] - mnew);
                    mr[r] = mnew;
                    lr[r] *= alpha[r];
                }
                #pragma unroll
                for (int db = 0; db < 8; db++)
                    #pragma unroll
                    for (int r = 0; r < 4; r++) of[db][r] *= alpha[r];
            }
            #pragma unroll
            for (int r = 0; r < 4; r++) {
                float rs = 0.0f;
                #pragma unroll
                for (int nb = 0; nb < 4; nb++) {
                    float p = __builtin_amdgcn_exp2f(sf[nb][r] - mr[r]);
                    sf[nb][r] = p;
                    rs += p;
                }
                lr[r] += rs;       // per-lane partial; reduced in epilogue
            }

            // P: C-layout -> wave-private LDS [m][s]
            #pragma unroll
            for (int nb = 0; nb < 4; nb++)
                #pragma unroll
                for (int r = 0; r < 4; r++)
                    Pw[(quad * 4 + r) * PSTR + nb * 16 + l16] = f2b(sf[nb][r]);
        }

        // ---- O += P V (swizzled vf reads from row-readable Vs[d][s])
        #pragma unroll
        for (int kc = 0; kc < 2; kc++) {
            bf16x8 pf = *(const bf16x8*)&Pw[l16 * PSTR + kc * 32 + quad * 8];
            #pragma unroll
            for (int db = 0; db < 8; db++) {
                const int u = (kc * 4 + quad) ^ (l16 & 7);
                bf16x8 vf = *(const bf16x8*)
                    &sm.a.Vs[(db * 16 + l16) * 64 + u * 8];
                of[db] = __builtin_amdgcn_mfma_f32_16x16x32_bf16(
                    pf, vf, of[db], 0, 0, 0);
            }
        }

        __syncthreads();           // all waves done READING Ks/Vs (tile kt)
        if (kt + 1 < ntiles) {
            write_tile();          // compiler waits vmcnt on kr/vr uses
            __syncthreads();       // tile kt+1 visible before next reads
        }
    }

    // ---- epilogue: lane-reduce lr, normalize, LDS transpose, float4 stores.
    // (last loop iter ended with the unconditional barrier -> union safe)
    float* Ow = sm.Ow + w * 16 * OSTR;     // wave-private 16x132 fp32
    float inv[4];
    #pragma unroll
    for (int r = 0; r < 4; r++) {
        float ls = lr[r];
        ls += __shfl_xor(ls, 1);
        ls += __shfl_xor(ls, 2);
        ls += __shfl_xor(ls, 4);
        ls += __shfl_xor(ls, 8);
        inv[r] = 1.0f / ls;
    }
    #pragma unroll
    for (int db = 0; db < 8; db++)
        #pragma unroll
        for (int r = 0; r < 4; r++)
            Ow[(quad * 4 + r) * OSTR + db * 16 + l16] = of[db][r] * inv[r];
    #pragma unroll
    for (int rg = 0; rg < 4; rg++) {
        const int rowl = rg * 4 + quad;
        float* op = out + ((size_t)(b * S_ + wrow0 + rowl)) * E_ + h * HD_;
        #pragma unroll
        for (int u = 0; u < 2; u++) {
            float4 v4 = *(const float4*)&Ow[rowl * OSTR + u * 64 + l16 * 4];
            *(float4*)(op + u * 64 + l16 * 4) = v4;
        }
    }
}

// ---------------------------------------------------------------------------
extern "C" void kernel_launch(void* const* d_in, const int* in_sizes, int n_in,
                              void* d_out, int out_size, void* d_ws, size_t ws_size,
                              hipStream_t stream)
{
    const float* x    = (const float*)d_in[0];   // fp32 (B,S,E)
    const float* W    = (const float*)d_in[1];   // fp32 (6144,2048)
    const float* bias = (const float*)d_in[2];   // fp32 (6144,)
    float* out = (float*)d_out;                  // fp32 (B,S,E)

    const size_t per = (size_t)B_ * NH_ * S_ * HD_;               // 8388608
    unsigned short* qb = (unsigned short*)d_ws;                   // [B][NH][S][HD]
    unsigned short* kb = qb + per;                                // [B][NH][S][HD]
    unsigned short* vt = kb + per;                                // [B][NH][HD][S]
    unsigned short* Xb = vt + per;                                // bf16 X
    unsigned short* Wb = Xb + (size_t)XN_;                        // bf16 W

    const int cvt_elems = XN_ + NQKV_ * E_;                       // 20971520
    cvt_bf16<<<cvt_elems / (256 * 8), 256, 0, stream>>>(x, W, Xb);

    dim3 gemm_grid((M_ / 128) * (NQKV_ / 256));                   // 32*24 = 768
    qkv_gemm<<<gemm_grid, 512, 0, stream>>>(Xb, Wb, bias, qb, kb, vt);

    attn_mfma<<<dim3(32 * 32), 256, 0, stream>>>(qb, kb, vt, out);
}

// Round 11
// 313.717 us; speedup vs baseline: 1.3261x; 1.3261x over previous
//
#include <hip/hip_runtime.h>

// MHA: cvt fp32->bf16 -> QKV GEMM (128x256 pipelined, LDS-coalesced epilogue,
//      V stored transposed) -> MFMA flash attention (gload_lds K/V staging)
// B=2 S=2048 E=2048 NH=16 HD=128 ROTARY=32 base=1e4 NEG_INF=-1e4
#define B_    2
#define S_    2048
#define E_    2048
#define NH_   16
#define HD_   128
#define NQKV_ 6144
#define M_    4096
#define XN_   (M_ * E_)          // 8388608 X elements
#define NPAN  (E_ / 32)          // 64 K-panels of 32

typedef short bf16x8 __attribute__((ext_vector_type(8)));   // 8 bf16 (4 VGPRs)
typedef float f32x4  __attribute__((ext_vector_type(4)));   // MFMA C/D

typedef const __attribute__((address_space(1))) void* gas_t; // global addrspace
typedef __attribute__((address_space(3))) void*       las_t; // LDS addrspace

__device__ inline float b2f(unsigned short u) {
    return __uint_as_float(((unsigned int)u) << 16);
}
__device__ inline unsigned short f2b(float f) {             // RNE f32->bf16
    unsigned int x = __float_as_uint(f);
    x = x + 0x7fffu + ((x >> 16) & 1u);
    return (unsigned short)(x >> 16);
}
__device__ inline unsigned int pk2(float lo, float hi) {
    return (unsigned int)f2b(lo) | ((unsigned int)f2b(hi) << 16);
}

// ---------------------------------------------------------------------------
// Kernel 0: one-shot fp32 -> bf16 of X (8.39M) and W (12.58M) into workspace.
// ---------------------------------------------------------------------------
__global__ __launch_bounds__(256) void cvt_bf16(
    const float* __restrict__ X,
    const float* __restrict__ W,
    unsigned short* __restrict__ O)      // [XN_ of X][W follows]
{
    const long i = (long)(blockIdx.x * 256 + threadIdx.x) * 8;
    const float* src = (i < XN_) ? (X + i) : (W + (i - XN_));
    const float4 a = *(const float4*)(src);
    const float4 b = *(const float4*)(src + 4);
    uint4 o = { pk2(a.x, a.y), pk2(a.z, a.w), pk2(b.x, b.y), pk2(b.z, b.w) };
    *(uint4*)(O + i) = o;
}

// ---------------------------------------------------------------------------
// Kernel 1: QKV = Xb * Wb^T + bias, RoPE fused. BYTE-IDENTICAL to round 8
// (measured 121 us, FETCH 100MB, MfmaUtil 36% = 2-barrier structure ceiling).
// ---------------------------------------------------------------------------
__global__ __launch_bounds__(512, 4) void qkv_gemm(
    const unsigned short* __restrict__ Xb,   // bf16 [4096][2048]
    const unsigned short* __restrict__ Wb,   // bf16 [6144][2048]
    const float* __restrict__ bias,
    unsigned short* __restrict__ qb,
    unsigned short* __restrict__ kb,
    unsigned short* __restrict__ vt)         // bf16 [B][NH][HD][S]
{
    union GS {
        struct {
            unsigned short As[3][128 * 32];  // 24 KiB
            unsigned short Bs[3][256 * 32];  // 48 KiB
        } s;
        unsigned short Eqk[128 * 264];       // 67584 B (epilogue reuse)
        unsigned short Ev [256 * 136];       // 69632 B (epilogue reuse)
    };
    __shared__ __align__(16) GS gs;

    const int t    = threadIdx.x;            // 0..511
    const int lane = t & 63;
    const int w    = t >> 6;                 // 0..7
    const int wr   = w >> 2;                 // 0..1  (m half, 64 rows)
    const int wc   = w & 3;                  // 0..3  (n quarter, 64 cols)
    const int quad = (lane >> 4) & 3;
    const int l16  = lane & 15;

    // XCD-aware 2D-locality swizzle (bid&7 = XCD, 768 = 8 * 96):
    // XCD x -> n-slab {3x..3x+2} (W slab 3MB, L2-resident), m streamed.
    const int xcd = (int)blockIdx.x & 7;
    const int j   = (int)blockIdx.x >> 3;    // 0..95
    const int m0  = (j / 3) * 128;           // 0..31 -> 128-row tiles
    const int n0  = (xcd * 3 + (j % 3)) * 256; // 0..23 -> 256-col tiles

    auto stageA = [&](int p) {
        const int sl = p % 3;
        const int k0 = p * 32;
        const int ub  = w * 64;
        const int u   = ub + lane;
        const int row = u >> 2;
        const int ko  = (u & 3) ^ ((row >> 1) & 3);
        __builtin_amdgcn_global_load_lds(
            (gas_t)(Xb + (size_t)(m0 + row) * E_ + k0 + ko * 8),
            (las_t)&gs.s.As[sl][ub * 8], 16, 0, 0);
    };
    auto stageB = [&](int p) {
        const int sl = p % 3;
        const int k0 = p * 32;
        #pragma unroll
        for (int c = 0; c < 2; c++) {
            const int ub  = c * 512 + w * 64;
            const int u   = ub + lane;
            const int row = u >> 2;
            const int ko  = (u & 3) ^ ((row >> 1) & 3);
            __builtin_amdgcn_global_load_lds(
                (gas_t)(Wb + (size_t)(n0 + row) * E_ + k0 + ko * 8),
                (las_t)&gs.s.Bs[sl][ub * 8], 16, 0, 0);
        }
    };

    f32x4 acc[4][4];
    #pragma unroll
    for (int i = 0; i < 4; i++)
        #pragma unroll
        for (int j2 = 0; j2 < 4; j2++)
            #pragma unroll
            for (int r = 0; r < 4; r++) acc[i][j2][r] = 0.0f;

    stageA(0); stageB(0);
    stageA(1); stageB(1);
    asm volatile("s_waitcnt vmcnt(0)" ::: "memory");
    __builtin_amdgcn_s_barrier();

    for (int p = 0; p < NPAN; p++) {
        const int sl = p % 3;
        bf16x8 af[4], bfv[4];

        #pragma unroll
        for (int mf = 0; mf < 4; mf++) {
            const int row = wr * 64 + mf * 16 + l16;
            af[mf] = *(const bf16x8*)&gs.s.As[sl][row * 32 + (quad ^ ((row >> 1) & 3)) * 8];
        }
        #pragma unroll
        for (int nf = 0; nf < 4; nf++) {
            const int rb = wc * 64 + nf * 16 + l16;
            bfv[nf] = *(const bf16x8*)&gs.s.Bs[sl][rb * 32 + (quad ^ ((rb >> 1) & 3)) * 8];
        }

        if (p + 2 < NPAN) {
            stageA(p + 2); stageB(p + 2);
            asm volatile("s_waitcnt vmcnt(3)" ::: "memory");   // p+1 landed
        } else {
            asm volatile("s_waitcnt vmcnt(0)" ::: "memory");   // tail
        }
        __builtin_amdgcn_s_barrier();
        __builtin_amdgcn_s_setprio(1);
        #pragma unroll
        for (int mf = 0; mf < 4; mf++)
            #pragma unroll
            for (int nf = 0; nf < 4; nf++)
                acc[mf][nf] = __builtin_amdgcn_mfma_f32_16x16x32_bf16(
                    af[mf], bfv[nf], acc[mf][nf], 0, 0, 0);
        __builtin_amdgcn_s_setprio(0);
        __builtin_amdgcn_s_barrier();
    }

    // ---- bias + fused RoPE on registers
    const int which = n0 >> 11;                   // 0=q 1=k 2=v (const/block)

    float bv[4];
    #pragma unroll
    for (int nf = 0; nf < 4; nf++) bv[nf] = bias[n0 + wc * 64 + nf * 16 + l16];
    #pragma unroll
    for (int mi = 0; mi < 4; mi++)
        #pragma unroll
        for (int nf = 0; nf < 4; nf++)
            #pragma unroll
            for (int r = 0; r < 4; r++) acc[mi][nf][r] += bv[nf];

    // RoPE: tile spans 2 heads; head-local d<64 quarters are wc==0 / wc==2.
    if ((wc & 1) == 0 && which < 2) {
        const float inv = exp2f(-0.83048202372184059f * (float)l16); // 1e4^(-d/16)
        #pragma unroll
        for (int mi = 0; mi < 4; mi++) {
            #pragma unroll
            for (int r = 0; r < 4; r++) {
                const int m = m0 + wr * 64 + mi * 16 + quad * 4 + r;
                const int sdx = m & (S_ - 1);
                float c, sn;
                __sincosf((float)sdx * inv, &sn, &c);
                const float u1 = acc[mi][0][r], u2 = acc[mi][1][r];
                acc[mi][0][r] = u1 * c - u2 * sn;
                acc[mi][1][r] = u1 * sn + u2 * c;
            }
        }
    }

    // ---- LDS-staged coalesced stores (main loop's final barrier passed;
    // all As/Bs reads retired -> union reuse safe).
    const int hb = (n0 >> 7) & 15;                // head base of this tile
    const int bb = m0 >> 11;
    const int sb = m0 & (S_ - 1);
    if (which < 2) {
        unsigned short* dst = (which == 0) ? qb : kb;
        unsigned short* E = gs.Eqk;               // [128][264]
        #pragma unroll
        for (int mi = 0; mi < 4; mi++) {
            const int m = wr * 64 + mi * 16 + quad * 4;
            #pragma unroll
            for (int nf = 0; nf < 4; nf++) {
                const int col = wc * 64 + nf * 16 + l16;
                #pragma unroll
                for (int r = 0; r < 4; r++)
                    E[(m + r) * 264 + col] = f2b(acc[mi][nf][r]);
            }
        }
        __syncthreads();
        const int em  = t >> 2;                   // 0..127
        const int ecg = (t & 3) * 8;              // chunk base
        unsigned short* orow =
            dst + ((size_t)(bb * NH_ + hb) * S_ + sb + em) * HD_;
        #pragma unroll
        for (int i = 0; i < 8; i++) {
            const int chunk = ecg + i;            // 0..31
            const int hh = chunk >> 4;            // +0/1 within tile
            const int d  = (chunk & 15) * 8;
            uint4 vv = *(const uint4*)&E[em * 264 + chunk * 8];
            *(uint4*)&orow[(size_t)hh * (HD_ * S_) + d] = vv;
        }
    } else {
        unsigned short* E = gs.Ev;                // [256][136]
        #pragma unroll
        for (int mi = 0; mi < 4; mi++) {
            const int m = wr * 64 + mi * 16 + quad * 4;
            #pragma unroll
            for (int nf = 0; nf < 4; nf++) {
                const int col = wc * 64 + nf * 16 + l16;
                #pragma unroll
                for (int r = 0; r < 4; r++)
                    E[col * 136 + m + r] = f2b(acc[mi][nf][r]);
            }
        }
        __syncthreads();
        const int col = t >> 1;                   // 0..255
        const int cb  = (t & 1) * 8;              // chunk base 0/8
        const int hh  = hb + (col >> 7);
        const int d   = col & 127;
        unsigned short* vrow =
            vt + ((size_t)(bb * NH_ + hh) * HD_ + d) * S_ + sb;
        #pragma unroll
        for (int i = 0; i < 8; i++) {
            const int chunk = cb + i;             // 0..15
            uint4 vv = *(const uint4*)&E[col * 136 + chunk * 8];
            *(uint4*)&vrow[chunk * 8] = vv;
        }
    }
}

// ---------------------------------------------------------------------------
// Kernel 2: MFMA causal flash attention. ROUND-10: revert to the round-8
// measured-good structure (gload_lds double-buffered K/V, one barrier/iter).
// Round-9's reg-staged single-buffer spilled kr/vr to scratch (WRITE_SIZE
// 545MB ~= 1024 x 256 x 128B x 16 iters) -> 190us. gload_lds avoids the
// VGPR round-trip entirely. One addition vs round-8: T5 s_setprio around
// the QK^T and PV MFMA clusters (2 independent blocks/CU + staggered waves
// = role diversity; m191 regime, +4-7%).
// Layouts (HW-verified 16x16x32_bf16): A[m=lane&15][k=quad*8+j];
// C/D row=quad*4+reg, col=lane&15.
// ---------------------------------------------------------------------------
#define PSTR 72
#define OSTR 132

__global__ __launch_bounds__(256, 2) void attn_mfma(
    const unsigned short* __restrict__ qb,
    const unsigned short* __restrict__ kb,
    const unsigned short* __restrict__ vt,
    float* __restrict__ out)
{
    union SM {
        struct {
            unsigned short Ks[2][64 * 128];    // 32768 B
            unsigned short Vs[2][128 * 64];    // 32768 B
            unsigned short Ps[4 * 16 * PSTR];  //  9216 B
        } a;                                   // 74752 B total
        float Ow[4 * 16 * OSTR];               // 33792 B (epilogue reuse)
    };
    __shared__ __align__(16) SM sm;

    const int bid  = blockIdx.x;
    const int qt   = 31 - (bid >> 5);       // 64-row q-tile, heavy-first
    const int bh   = bid & 31;
    const int b    = bh >> 4;
    const int h    = bh & 15;
    const int t    = threadIdx.x;
    const int lane = t & 63;
    const int w    = t >> 6;
    const int quad = lane >> 4;
    const int l16  = lane & 15;

    const int wrow0  = qt * 64 + w * 16;    // wave q-row base (16 rows)
    const int ntiles = qt + 1;              // K tiles of 64

    unsigned short* Pw = sm.a.Ps + w * 16 * PSTR;

    // staging lane maps: K rows = s (256B each, 16 lanes); V rows = d (128B, 8)
    const int ksrow = w * 4 + (lane >> 4);  // + c*16
    const int ksu   = lane & 15;
    const int vdrow = w * 8 + (lane >> 3);  // + c*32
    const int vsu   = lane & 7;

    auto stage = [&](int kt2, int bsel) {
        const int s2 = kt2 * 64;
        #pragma unroll
        for (int c = 0; c < 4; c++) {
            const int srow = c * 16 + ksrow;
            __builtin_amdgcn_global_load_lds(
                (gas_t)(kb + ((size_t)(bh * S_ + s2 + srow)) * HD_
                        + (ksu ^ (srow & 7)) * 8),
                (las_t)&sm.a.Ks[bsel][(c * 16 + w * 4) * 128], 16, 0, 0);
        }
        #pragma unroll
        for (int c = 0; c < 4; c++) {
            const int drow = c * 32 + vdrow;
            __builtin_amdgcn_global_load_lds(
                (gas_t)(vt + ((size_t)(bh * HD_ + drow)) * S_ + s2
                        + (vsu ^ (drow & 7)) * 8),
                (las_t)&sm.a.Vs[bsel][(c * 32 + w * 8) * 64], 16, 0, 0);
        }
    };

    // Q A-fragments from global: k = c*32 + quad*8 + j
    bf16x8 qf[4];
    {
        const unsigned short* qp =
            qb + ((size_t)(bh * S_ + wrow0 + l16)) * HD_ + quad * 8;
        #pragma unroll
        for (int c = 0; c < 4; c++)
            qf[c] = *(const bf16x8*)(qp + c * 32);
    }

    f32x4 of[8];
    #pragma unroll
    for (int db = 0; db < 8; db++)
        #pragma unroll
        for (int r = 0; r < 4; r++) of[db][r] = 0.0f;
    float mr[4], lr[4];
    #pragma unroll
    for (int r = 0; r < 4; r++) { mr[r] = -1e30f; lr[r] = 0.0f; }

    // log2-domain softmax: scale' = (1/sqrt(128))*log2(e), mask' = -1e4*log2(e)
    const float scale2 = 0.12751744459892879f;
    const float mneg2  = -14426.950408889634f;

    stage(0, 0);
    __syncthreads();                 // vmcnt(0) + barrier: tile 0 landed
    int cur = 0;

    for (int kt = 0; kt < ntiles; kt++) {
        const int s0 = kt * 64;
        if (kt + 1 < ntiles) stage(kt + 1, cur ^ 1);   // hidden under compute

        // ---- S = Q K^T (swizzled kf reads)
        f32x4 sf[4];
        #pragma unroll
        for (int nb = 0; nb < 4; nb++)
            #pragma unroll
            for (int r = 0; r < 4; r++) sf[nb][r] = 0.0f;
        __builtin_amdgcn_s_setprio(1);
        #pragma unroll
        for (int c = 0; c < 4; c++) {
            #pragma unroll
            for (int nb = 0; nb < 4; nb++) {
                const int u = (c * 4 + quad) ^ (l16 & 7);
                bf16x8 kf = *(const bf16x8*)
                    &sm.a.Ks[cur][(nb * 16 + l16) * 128 + u * 8];
                sf[nb] = __builtin_amdgcn_mfma_f32_16x16x32_bf16(
                    qf[c], kf, sf[nb], 0, 0, 0);
            }
        }
        __builtin_amdgcn_s_setprio(0);

        // ---- scale + causal mask, log2 domain
        const bool need_mask = (s0 + 63 > wrow0);
        {
            const int qr0 = wrow0 + quad * 4;
            #pragma unroll
            for (int nb = 0; nb < 4; nb++) {
                const int kcol = s0 + nb * 16 + l16;
                #pragma unroll
                for (int r = 0; r < 4; r++) {
                    float s = sf[nb][r] * scale2;
                    if (need_mask && kcol > qr0 + r) s += mneg2;
                    sf[nb][r] = s;
                }
            }
        }

        // ---- online softmax (16-lane max reduce; lr partials; deferred
        //      rescale when no row max grew)
        {
            float mt4[4];
            #pragma unroll
            for (int r = 0; r < 4; r++) {
                float mt = fmaxf(fmaxf(sf[0][r], sf[1][r]),
                                 fmaxf(sf[2][r], sf[3][r]));
                mt = fmaxf(mt, __shfl_xor(mt, 1));
                mt = fmaxf(mt, __shfl_xor(mt, 2));
                mt = fmaxf(mt, __shfl_xor(mt, 4));
                mt = fmaxf(mt, __shfl_xor(mt, 8));
                mt4[r] = mt;
            }
            const bool grew = (mt4[0] > mr[0]) || (mt4[1] > mr[1]) ||
                              (mt4[2] > mr[2]) || (mt4[3] > mr[3]);
            if (__any(grew)) {
                float alpha[4];
                #pragma unroll
                for (int r = 0; r < 4; r++) {
                    const float mnew = fmaxf(mr[r], mt4[r]);
                    alpha[r] = __builtin_amdgcn_exp2f(mr[r] - mnew);
                    mr[r] = mnew;
                    lr[r] *= alpha[r];
                }
                #pragma unroll
                for (int db = 0; db < 8; db++)
                    #pragma unroll
                    for (int r = 0; r < 4; r++) of[db][r] *= alpha[r];
            }
            #pragma unroll
            for (int r = 0; r < 4; r++) {
                float rs = 0.0f;
                #pragma unroll
                for (int nb = 0; nb < 4; nb++) {
                    float p = __builtin_amdgcn_exp2f(sf[nb][r] - mr[r]);
                    sf[nb][r] = p;
                    rs += p;
                }
                lr[r] += rs;       // per-lane partial; reduced in epilogue
            }

            // P: C-layout -> wave-private LDS [m][s]
            #pragma unroll
            for (int nb = 0; nb < 4; nb++)
                #pragma unroll
                for (int r = 0; r < 4; r++)
                    Pw[(quad * 4 + r) * PSTR + nb * 16 + l16] = f2b(sf[nb][r]);
        }

        // ---- O += P V (swizzled vf reads from row-readable Vs[d][s])
        __builtin_amdgcn_s_setprio(1);
        #pragma unroll
        for (int kc = 0; kc < 2; kc++) {
            bf16x8 pf = *(const bf16x8*)&Pw[l16 * PSTR + kc * 32 + quad * 8];
            #pragma unroll
            for (int db = 0; db < 8; db++) {
                const int u = (kc * 4 + quad) ^ (l16 & 7);
                bf16x8 vf = *(const bf16x8*)
                    &sm.a.Vs[cur][(db * 16 + l16) * 64 + u * 8];
                of[db] = __builtin_amdgcn_mfma_f32_16x16x32_bf16(
                    pf, vf, of[db], 0, 0, 0);
            }
        }
        __builtin_amdgcn_s_setprio(0);

        __syncthreads();           // drains my stage(t+1) + all waves done
        cur ^= 1;
    }

    // ---- epilogue: lane-reduce lr, normalize, LDS transpose, float4 stores.
    float* Ow = sm.Ow + w * 16 * OSTR;     // wave-private 16x132 fp32
    float inv[4];
    #pragma unroll
    for (int r = 0; r < 4; r++) {
        float ls = lr[r];
        ls += __shfl_xor(ls, 1);
        ls += __shfl_xor(ls, 2);
        ls += __shfl_xor(ls, 4);
        ls += __shfl_xor(ls, 8);
        inv[r] = 1.0f / ls;
    }
    #pragma unroll
    for (int db = 0; db < 8; db++)
        #pragma unroll
        for (int r = 0; r < 4; r++)
            Ow[(quad * 4 + r) * OSTR + db * 16 + l16] = of[db][r] * inv[r];
    #pragma unroll
    for (int rg = 0; rg < 4; rg++) {
        const int rowl = rg * 4 + quad;
        float* op = out + ((size_t)(b * S_ + wrow0 + rowl)) * E_ + h * HD_;
        #pragma unroll
        for (int u = 0; u < 2; u++) {
            float4 v4 = *(const float4*)&Ow[rowl * OSTR + u * 64 + l16 * 4];
            *(float4*)(op + u * 64 + l16 * 4) = v4;
        }
    }
}

// ---------------------------------------------------------------------------
extern "C" void kernel_launch(void* const* d_in, const int* in_sizes, int n_in,
                              void* d_out, int out_size, void* d_ws, size_t ws_size,
                              hipStream_t stream)
{
    const float* x    = (const float*)d_in[0];   // fp32 (B,S,E)
    const float* W    = (const float*)d_in[1];   // fp32 (6144,2048)
    const float* bias = (const float*)d_in[2];   // fp32 (6144,)
    float* out = (float*)d_out;                  // fp32 (B,S,E)

    const size_t per = (size_t)B_ * NH_ * S_ * HD_;               // 8388608
    unsigned short* qb = (unsigned short*)d_ws;                   // [B][NH][S][HD]
    unsigned short* kb = qb + per;                                // [B][NH][S][HD]
    unsigned short* vt = kb + per;                                // [B][NH][HD][S]
    unsigned short* Xb = vt + per;                                // bf16 X
    unsigned short* Wb = Xb + (size_t)XN_;                        // bf16 W

    const int cvt_elems = XN_ + NQKV_ * E_;                       // 20971520
    cvt_bf16<<<cvt_elems / (256 * 8), 256, 0, stream>>>(x, W, Xb);

    dim3 gemm_grid((M_ / 128) * (NQKV_ / 256));                   // 32*24 = 768
    qkv_gemm<<<gemm_grid, 512, 0, stream>>>(Xb, Wb, bias, qb, kb, vt);

    attn_mfma<<<dim3(32 * 32), 256, 0, stream>>>(qb, kb, vt, out);
}